// Round 1
// baseline (1116.186 us; speedup 1.0000x reference)
//
#include <hip/hip_runtime.h>
#include <stdint.h>

#define NN 50000
#define EE 625000
#define CC 128
#define HH 256
#define LL 4
#define NPAD 50016

// fq building blocks: everything lives on the k/16 grid, k in [-128,127].
// rintf == round-half-even == jnp.round. All arithmetic exact in fp32 (<2^24).
__device__ __forceinline__ float qbf(float x){
  return fminf(127.f, fmaxf(-128.f, rintf(x*16.f)));
}
__device__ __forceinline__ float rq16(float t){   // fq of (t/256) in value space, returns int-valued float*16... i.e. k
  return fminf(127.f, fmaxf(-128.f, rintf(t*0.0625f)));
}

// ---------------- param quantization ----------------
__global__ void k_qbig(const float* __restrict__ W1, const float* __restrict__ W2,
                       float* __restrict__ W1f, float* __restrict__ W2f){
  int i = blockIdx.x*256 + threadIdx.x;
  if (i < LL*CC*HH){ W1f[i] = qbf(W1[i]); W2f[i] = qbf(W2[i]); }
}

struct QS { const float* s; float* d; int n; float m; };
struct QSArgs { QS q[14]; };

__global__ void k_qsmall(QSArgs a){
  for (int r=0;r<14;++r){
    QS qs = a.q[r];
    for (int i = blockIdx.x*blockDim.x + threadIdx.x; i < qs.n; i += gridDim.x*blockDim.x)
      qs.d[i] = qs.m * qbf(qs.s[i]);
  }
}

// ---------------- encoders ----------------
__global__ __launch_bounds__(256) void k_node_enc(
    const float* __restrict__ x, const float* __restrict__ nW,
    const float* __restrict__ nb16, const float* __restrict__ bnw,
    const float* __restrict__ bnb16, short* __restrict__ h0){
  int idx = blockIdx.x*256 + threadIdx.x;          // grid exact: N*C/256
  int n = idx >> 7, c = idx & 127;
  float x0 = qbf(x[n*3]), x1 = qbf(x[n*3+1]), x2 = qbf(x[n*3+2]);
  float S = x0*nW[c] + x1*nW[CC+c] + x2*nW[2*CC+c];
  float v1 = rq16(S + nb16[c]);                    // qlin
  float v2 = rq16(v1*bnw[c] + bnb16[c]);           // qbn
  h0[idx] = (short)v2;
}

__global__ void k_qedge(const float* __restrict__ ea, float4* __restrict__ eqf){
  int e = blockIdx.x*256 + threadIdx.x;
  if (e >= EE) return;
  float4 v = ((const float4*)ea)[e];
  eqf[e] = make_float4(qbf(v.x), qbf(v.y), qbf(v.z), qbf(v.w));
}

// ---------------- CSR build ----------------
__global__ void k_deg(const int* __restrict__ ei, int* __restrict__ deg){
  int e = blockIdx.x*256 + threadIdx.x;
  if (e < EE) atomicAdd(&deg[ei[EE + e]], 1);
}

__global__ __launch_bounds__(256) void k_scanA(const int* __restrict__ deg,
                                               int* __restrict__ offI,
                                               int* __restrict__ btot){
  __shared__ int sh[256];
  int t = threadIdx.x;
  int base = blockIdx.x*1024 + t*4;
  int v[4]; int s = 0;
  #pragma unroll
  for (int i=0;i<4;++i){ v[i] = (base+i < NN) ? deg[base+i] : 0; s += v[i]; }
  sh[t] = s; __syncthreads();
  for (int off=1; off<256; off<<=1){
    int xv = (t>=off) ? sh[t-off] : 0;
    __syncthreads();
    sh[t] += xv;
    __syncthreads();
  }
  int run = (t>0) ? sh[t-1] : 0;
  #pragma unroll
  for (int i=0;i<4;++i){ run += v[i]; if (base+i < NN) offI[base+i] = run; }
  if (t==255) btot[blockIdx.x] = sh[255];
}

__global__ void k_scanB(const int* __restrict__ btot, int* __restrict__ boff, int nblk){
  if (threadIdx.x==0 && blockIdx.x==0){
    int run = 0;
    for (int b=0;b<nblk;++b){ int v = btot[b]; boff[b] = run; run += v; }
  }
}

__global__ void k_scanC(const int* __restrict__ boff, const int* __restrict__ deg,
                        int* __restrict__ offI, int* __restrict__ cursor){
  int i = blockIdx.x*256 + threadIdx.x;
  if (i < NN){
    int v = offI[i] + boff[i>>10];
    offI[i] = v;              // global inclusive prefix
    cursor[i] = v - deg[i];   // segment start
  }
}

__global__ void k_fill(const int* __restrict__ ei, int* __restrict__ cursor,
                       int2* __restrict__ adj){
  int e = blockIdx.x*256 + threadIdx.x;
  if (e < EE){
    int tgt = ei[EE + e];
    int p = atomicAdd(&cursor[tgt], 1);
    adj[p] = make_int2(ei[e], e);   // (src, eid)
  }
}

// ---------------- per-layer: message + segment-sum (gather, no atomics) ----------------
__global__ __launch_bounds__(256) void k_msg(
    const int* __restrict__ offI, const int* __restrict__ deg,
    const int2* __restrict__ adj, const float4* __restrict__ eqf,
    const float* __restrict__ ewf, const float* __restrict__ eb16,
    const float* __restrict__ ebnw, const float* __restrict__ ebnb16,
    const short* __restrict__ h_in, signed char* __restrict__ uq){
  int n = blockIdx.x*2 + (threadIdx.x >> 7);
  int c = threadIdx.x & 127;
  float w0 = ewf[c], w1 = ewf[CC+c], w2 = ewf[2*CC+c], w3 = ewf[3*CC+c];
  float eb = eb16[c], bw = ebnw[c], bb = ebnb16[c];
  int end = offI[n];
  int start = end - deg[n];
  float acc = 0.f;
  for (int k = start; k < end; ++k){
    int2 se = adj[k];
    float4 q = eqf[se.y];
    // recompute quantized edge feature e_c (exact)
    float S  = q.x*w0 + q.y*w1 + q.z*w2 + q.w*w3;
    float v1 = rq16(S + eb);
    float ec = rq16(v1*bw + bb);
    float hv = (float)h_in[se.x*CC + c];
    hv = fminf(127.f, fmaxf(-128.f, hv));          // fq(h[src])
    float m = fminf(127.f, fmaxf(0.f, hv + ec));   // fq(relu(.))
    acc += m;                                       // exact int sum
  }
  uq[n*CC + c] = (signed char)fminf(acc, 127.f);   // u = fq(agg), agg>=0
}

// ---------------- per-layer: fused ObjectModel (GEMM1+BN+ReLU+GEMM2+residual) ----------------
__global__ __launch_bounds__(256) void k_om(
    int l, const signed char* __restrict__ uq,
    const float* __restrict__ W1f, const float* __restrict__ b1q16,
    const float* __restrict__ bnwf, const float* __restrict__ bnb16,
    const float* __restrict__ W2f, const float* __restrict__ b2q16,
    const short* __restrict__ h_in, short* __restrict__ h_out){
  __shared__ float uL[32][132];   // padded: stride%32=4 -> conflict-free
  __shared__ float zL[32][260];
  int t = threadIdx.x;
  int nb = blockIdx.x * 32;
  {
    const int4* up = (const int4*)(uq + (size_t)nb*CC);
    int4 raw = up[t];
    const signed char* pb = (const signed char*)&raw;
    int base = t*16;
    #pragma unroll
    for (int j=0;j<16;++j){
      int flat = base + j;
      uL[flat>>7][flat&127] = (float)pb[j];
    }
  }
  __syncthreads();
  int nq = t & 7, hq = t >> 3;    // 4 nodes {nq+8i}, 8 outputs {hq*8+j}
  const float* W1p = W1f + l*CC*HH;
  float acc[4][8];
  #pragma unroll
  for (int i=0;i<4;++i){
    #pragma unroll
    for (int j=0;j<8;++j) acc[i][j] = b1q16[l*HH + hq*8 + j];
  }
  for (int c=0;c<CC;++c){
    float4 wA = *(const float4*)(W1p + c*HH + hq*8);
    float4 wB = *(const float4*)(W1p + c*HH + hq*8 + 4);
    float uu[4];
    #pragma unroll
    for (int i=0;i<4;++i) uu[i] = uL[nq + 8*i][c];
    #pragma unroll
    for (int i=0;i<4;++i){
      acc[i][0] += uu[i]*wA.x; acc[i][1] += uu[i]*wA.y;
      acc[i][2] += uu[i]*wA.z; acc[i][3] += uu[i]*wA.w;
      acc[i][4] += uu[i]*wB.x; acc[i][5] += uu[i]*wB.y;
      acc[i][6] += uu[i]*wB.z; acc[i][7] += uu[i]*wB.w;
    }
  }
  {
    float bw[8], bb[8];
    #pragma unroll
    for (int j=0;j<8;++j){ bw[j] = bnwf[l*HH + hq*8 + j]; bb[j] = bnb16[l*HH + hq*8 + j]; }
    #pragma unroll
    for (int i=0;i<4;++i){
      #pragma unroll
      for (int j=0;j<8;++j){
        float v1 = rq16(acc[i][j]);            // qlin requant
        float v2 = rq16(v1*bw[j] + bb[j]);     // qbn
        zL[nq + 8*i][hq*8 + j] = fmaxf(v2, 0.f); // fq(relu)
      }
    }
  }
  __syncthreads();
  int cq = hq;                    // 4 outputs {cq*4+j}
  const float* W2p = W2f + l*HH*CC;
  float a2[4][4];
  #pragma unroll
  for (int i=0;i<4;++i){
    #pragma unroll
    for (int j=0;j<4;++j) a2[i][j] = b2q16[l*CC + cq*4 + j];
  }
  for (int h=0;h<HH;++h){
    float4 w = *(const float4*)(W2p + h*CC + cq*4);
    float zz[4];
    #pragma unroll
    for (int i=0;i<4;++i) zz[i] = zL[nq + 8*i][h];
    #pragma unroll
    for (int i=0;i<4;++i){
      a2[i][0] += zz[i]*w.x; a2[i][1] += zz[i]*w.y;
      a2[i][2] += zz[i]*w.z; a2[i][3] += zz[i]*w.w;
    }
  }
  #pragma unroll
  for (int i=0;i<4;++i){
    int node = nb + nq + 8*i;
    if (node < NN){
      const short* hi = h_in + (size_t)node*CC + cq*4;
      short* ho = h_out + (size_t)node*CC + cq*4;
      #pragma unroll
      for (int j=0;j<4;++j){
        float v = rq16(a2[i][j]);               // z = fq(qlin(...))
        ho[j] = (short)(hi[j] + (int)v);        // residual
      }
    }
  }
}

// ---------------- pool + head ----------------
__global__ void k_pool(const short* __restrict__ h, int* __restrict__ pooled){
  int gid = blockIdx.x*256 + threadIdx.x;
  int c = gid & 127;
  int step = (gridDim.x*256) >> 7;
  int s = 0;
  for (int n = gid>>7; n < NN; n += step) s += h[(size_t)n*CC + c];
  atomicAdd(&pooled[c], s);
}

__global__ void k_final(const int* __restrict__ pooled, const float* __restrict__ fcwf,
                        const float* __restrict__ fcb16, float* __restrict__ out){
  __shared__ float red[128];
  int t = threadIdx.x;
  int sc = pooled[t];
  double m = (double)sc / (double)NN;           // pooled*16 in value space
  float pq = fminf(127.f, fmaxf(-128.f, (float)rint(m)));  // fq(pooled)
  red[t] = pq * fcwf[t];
  __syncthreads();
  for (int o=64;o>0;o>>=1){ if (t<o) red[t] += red[t+o]; __syncthreads(); }
  if (t==0){
    float v = rq16(red[0] + fcb16[0]);          // qlin head
    float o1 = v * 0.0625f;
    float sg = 1.f/(1.f + expf(-o1));           // sigmoid
    float oq = fminf(127.f, fmaxf(-128.f, rintf(sg*16.f)));  // fq
    out[0] = oq * 0.0625f;
  }
}

extern "C" void kernel_launch(void* const* d_in, const int* in_sizes, int n_in,
                              void* d_out, int out_size, void* d_ws, size_t ws_size,
                              hipStream_t stream){
  (void)in_sizes; (void)n_in; (void)out_size; (void)ws_size;
  const float* x   = (const float*)d_in[0];
  const float* ea  = (const float*)d_in[1];
  const int*   ei  = (const int*)d_in[2];
  const float* W1  = (const float*)d_in[11];
  const float* W2  = (const float*)d_in[15];

  char* w = (char*)d_ws;
  auto alloc = [&](size_t bytes)->char*{
    char* p = w; w += (bytes + 255) & ~(size_t)255; return p;
  };
  short* h0        = (short*)alloc((size_t)NPAD*CC*2);
  short* h1        = (short*)alloc((size_t)NPAD*CC*2);
  signed char* uq  = (signed char*)alloc((size_t)NPAD*CC);
  float4* eqf      = (float4*)alloc((size_t)EE*16);
  int2* adj        = (int2*)alloc((size_t)EE*8);
  int* deg         = (int*)alloc(NN*4);
  int* offI        = (int*)alloc(NN*4);
  int* cursor      = (int*)alloc(NN*4);
  int* btot        = (int*)alloc(64*4);
  int* boff        = (int*)alloc(64*4);
  float* W1f       = (float*)alloc((size_t)LL*CC*HH*4);
  float* W2f       = (float*)alloc((size_t)LL*HH*CC*4);
  float* nodeWf    = (float*)alloc(3*CC*4);
  float* nb16f     = (float*)alloc(CC*4);
  float* nbnwf     = (float*)alloc(CC*4);
  float* nbnb16f   = (float*)alloc(CC*4);
  float* ewf       = (float*)alloc(4*CC*4);
  float* eb16f     = (float*)alloc(CC*4);
  float* ebnwf     = (float*)alloc(CC*4);
  float* ebnb16f   = (float*)alloc(CC*4);
  float* b1q16f    = (float*)alloc(LL*HH*4);
  float* bnwf      = (float*)alloc(LL*HH*4);
  float* bnb16f    = (float*)alloc(LL*HH*4);
  float* b2q16f    = (float*)alloc(LL*CC*4);
  float* fcwf      = (float*)alloc(CC*4);
  float* fcb16f    = (float*)alloc(256);
  int* pooled      = (int*)alloc(CC*4);

  hipMemsetAsync(deg, 0, NN*4, stream);
  hipMemsetAsync(pooled, 0, CC*4, stream);

  k_qbig<<<(LL*CC*HH + 255)/256, 256, 0, stream>>>(W1, W2, W1f, W2f);

  QSArgs qa;
  auto setq = [&](int r, int idx, float* d, int n, float m){
    qa.q[r].s = (const float*)d_in[idx]; qa.q[r].d = d; qa.q[r].n = n; qa.q[r].m = m;
  };
  setq(0, 3,  nodeWf,  3*CC, 1.f);
  setq(1, 4,  nb16f,   CC,   16.f);
  setq(2, 5,  ewf,     4*CC, 1.f);
  setq(3, 6,  eb16f,   CC,   16.f);
  setq(4, 7,  nbnwf,   CC,   1.f);
  setq(5, 8,  nbnb16f, CC,   16.f);
  setq(6, 9,  ebnwf,   CC,   1.f);
  setq(7, 10, ebnb16f, CC,   16.f);
  setq(8, 12, b1q16f,  LL*HH, 16.f);
  setq(9, 13, bnwf,    LL*HH, 1.f);
  setq(10,14, bnb16f,  LL*HH, 16.f);
  setq(11,16, b2q16f,  LL*CC, 16.f);
  setq(12,17, fcwf,    CC,   1.f);
  setq(13,18, fcb16f,  1,    16.f);
  k_qsmall<<<4, 256, 0, stream>>>(qa);

  k_node_enc<<<(NN*CC)/256, 256, 0, stream>>>(x, nodeWf, nb16f, nbnwf, nbnb16f, h0);
  k_qedge<<<(EE+255)/256, 256, 0, stream>>>(ea, eqf);
  k_deg<<<(EE+255)/256, 256, 0, stream>>>(ei, deg);
  int nblk = (NN + 1023)/1024;
  k_scanA<<<nblk, 256, 0, stream>>>(deg, offI, btot);
  k_scanB<<<1, 64, 0, stream>>>(btot, boff, nblk);
  k_scanC<<<(NN+255)/256, 256, 0, stream>>>(boff, deg, offI, cursor);
  k_fill<<<(EE+255)/256, 256, 0, stream>>>(ei, cursor, adj);

  for (int l=0;l<LL;++l){
    const short* hi = (l & 1) ? h1 : h0;
    short* ho       = (l & 1) ? h0 : h1;
    k_msg<<<NN/2, 256, 0, stream>>>(offI, deg, adj, eqf, ewf, eb16f, ebnwf, ebnb16f, hi, uq);
    k_om<<<(NN+31)/32, 256, 0, stream>>>(l, uq, W1f, b1q16f, bnwf, bnb16f, W2f, b2q16f, hi, ho);
  }
  // after 4 layers the live buffer is h0
  k_pool<<<512, 256, 0, stream>>>(h0, pooled);
  k_final<<<1, 128, 0, stream>>>(pooled, fcwf, fcb16f, (float*)d_out);
}

// Round 2
// 608.852 us; speedup vs baseline: 1.8333x; 1.8333x over previous
//
#include <hip/hip_runtime.h>
#include <stdint.h>

#define NN 50000
#define EE 625000
#define CC 128
#define HH 256
#define LL 4
#define NPAD 50048   // multiple of 64 for k_om tiles

typedef __attribute__((ext_vector_type(8))) short bf16x8;
typedef __attribute__((ext_vector_type(4))) float f32x4;

// Everything lives on the k/16 grid, k in [-128,127]; rintf == round-half-even
// == jnp.round. All sums < 2^24 -> exact fp32 (and exact bf16 MFMA: inputs are
// integers |x|<=128, products <=16129, K-sums <=4.13e6 < 2^24).
__device__ __forceinline__ float qbf(float x){
  return fminf(127.f, fmaxf(-128.f, rintf(x*16.f)));
}
__device__ __forceinline__ float rq16(float t){
  return fminf(127.f, fmaxf(-128.f, rintf(t*0.0625f)));
}
__device__ __forceinline__ ushort f2bf(float v){  // exact for our small ints
  return (ushort)(__float_as_uint(v) >> 16);
}

// ---------------- param quantization ----------------
__global__ void k_qbig(const float* __restrict__ W1, const float* __restrict__ W2,
                       ushort* __restrict__ W1t, ushort* __restrict__ W2t){
  int i = blockIdx.x*256 + threadIdx.x;
  if (i >= LL*CC*HH) return;
  {  // W1 [L][C][H] -> W1t [L][H][C] bf16
    float v = qbf(W1[i]);
    int l = i / (CC*HH); int r = i - l*CC*HH; int c = r / HH; int hh = r - c*HH;
    W1t[((size_t)l*HH + hh)*CC + c] = f2bf(v);
  }
  {  // W2 [L][H][C] -> W2t [L][C][H] bf16
    float v = qbf(W2[i]);
    int l = i / (HH*CC); int r = i - l*HH*CC; int hh = r / CC; int c = r - hh*CC;
    W2t[((size_t)l*CC + c)*HH + hh] = f2bf(v);
  }
}

struct QS { const float* s; float* d; int n; float m; };
struct QSArgs { QS q[14]; };

__global__ void k_qsmall(QSArgs a){
  for (int r=0;r<14;++r){
    QS qs = a.q[r];
    for (int i = blockIdx.x*blockDim.x + threadIdx.x; i < qs.n; i += gridDim.x*blockDim.x)
      qs.d[i] = qs.m * qbf(qs.s[i]);
  }
}

// ---------------- node encoder ----------------
__global__ __launch_bounds__(256) void k_node_enc(
    const float* __restrict__ x, const float* __restrict__ nW,
    const float* __restrict__ nb16, const float* __restrict__ bnw,
    const float* __restrict__ bnb16, short* __restrict__ h0,
    signed char* __restrict__ hq8){
  int idx = blockIdx.x*256 + threadIdx.x;          // grid exact: N*C/256
  int n = idx >> 7, c = idx & 127;
  float x0 = qbf(x[n*3]), x1 = qbf(x[n*3+1]), x2 = qbf(x[n*3+2]);
  float S = x0*nW[c] + x1*nW[CC+c] + x2*nW[2*CC+c];
  float v1 = rq16(S + nb16[c]);
  float v2 = rq16(v1*bnw[c] + bnb16[c]);
  h0[idx] = (short)v2;
  hq8[idx] = (signed char)v2;   // already in [-128,127]
}

// ---------------- CSR build ----------------
__global__ void k_deg(const int* __restrict__ ei, int* __restrict__ deg){
  int e = blockIdx.x*256 + threadIdx.x;
  if (e < EE) atomicAdd(&deg[ei[EE + e]], 1);
}

__global__ __launch_bounds__(256) void k_scanA(const int* __restrict__ deg,
                                               int* __restrict__ offI,
                                               int* __restrict__ btot){
  __shared__ int sh[256];
  int t = threadIdx.x;
  int base = blockIdx.x*1024 + t*4;
  int v[4]; int s = 0;
  #pragma unroll
  for (int i=0;i<4;++i){ v[i] = (base+i < NN) ? deg[base+i] : 0; s += v[i]; }
  sh[t] = s; __syncthreads();
  for (int off=1; off<256; off<<=1){
    int xv = (t>=off) ? sh[t-off] : 0;
    __syncthreads();
    sh[t] += xv;
    __syncthreads();
  }
  int run = (t>0) ? sh[t-1] : 0;
  #pragma unroll
  for (int i=0;i<4;++i){ run += v[i]; if (base+i < NN) offI[base+i] = run; }
  if (t==255) btot[blockIdx.x] = sh[255];
}

__global__ void k_scanB(const int* __restrict__ btot, int* __restrict__ boff, int nblk){
  if (threadIdx.x==0 && blockIdx.x==0){
    int run = 0;
    for (int b=0;b<nblk;++b){ int v = btot[b]; boff[b] = run; run += v; }
  }
}

__global__ void k_scanC(const int* __restrict__ boff, const int* __restrict__ deg,
                        int* __restrict__ offI, int* __restrict__ cursor){
  int i = blockIdx.x*256 + threadIdx.x;
  if (i < NN){
    int v = offI[i] + boff[i>>10];
    offI[i] = v;
    cursor[i] = v - deg[i];
  }
}

__global__ void k_fill(const int* __restrict__ ei, int* __restrict__ cursor,
                       int* __restrict__ srcoff, int* __restrict__ eidc){
  int e = blockIdx.x*256 + threadIdx.x;
  if (e < EE){
    int tgt = ei[EE + e];
    int p = atomicAdd(&cursor[tgt], 1);
    srcoff[p] = ei[e] * CC;
    eidc[p] = e;
  }
}

// quantized edge attrs in CSR order (float4 of int-valued k)
__global__ void k_eperm(const int* __restrict__ eidc, const float* __restrict__ ea,
                        float4* __restrict__ qcsr){
  int p = blockIdx.x*256 + threadIdx.x;
  if (p >= EE) return;
  const float4 v = ((const float4*)ea)[eidc[p]];
  qcsr[p] = make_float4(qbf(v.x), qbf(v.y), qbf(v.z), qbf(v.w));
}

// PRE path: fully materialize edge feature e (int8) in CSR order, once.
__global__ __launch_bounds__(256) void k_eenc(
    const float4* __restrict__ qcsr,
    const float* __restrict__ ewf, const float* __restrict__ eb16,
    const float* __restrict__ ebnw, const float* __restrict__ ebnb16,
    signed char* __restrict__ eq){
  int p = blockIdx.x*2 + (threadIdx.x >> 7);
  int c = threadIdx.x & 127;
  float4 q = qcsr[p];
  float S  = q.x*ewf[c] + q.y*ewf[CC+c] + q.z*ewf[2*CC+c] + q.w*ewf[3*CC+c];
  float v1 = rq16(S + eb16[c]);
  float ec = rq16(v1*ebnw[c] + ebnb16[c]);
  eq[(size_t)p*CC + c] = (signed char)ec;
}

// ---------------- per-layer message+aggregate (gather CSR, no atomics) ------
// one wave per node, 2 channels per lane; exact integer math
template<int PRE>
__global__ __launch_bounds__(256) void k_msg(
    const int* __restrict__ offI, const int* __restrict__ deg_,
    const int* __restrict__ srcoff, const float4* __restrict__ qcsr,
    const signed char* __restrict__ eq,
    const float* __restrict__ ewf, const float* __restrict__ eb16,
    const float* __restrict__ ebnw, const float* __restrict__ ebnb16,
    const signed char* __restrict__ hq8, ushort* __restrict__ u_bf){
  int n = blockIdx.x*4 + (threadIdx.x >> 6);
  int lane = threadIdx.x & 63;
  int c0 = lane*2;
  float w0a,w1a,w2a,w3a,eba,bwa,bba, w0b,w1b,w2b,w3b,ebb,bwb,bbb;
  if (!PRE){
    w0a=ewf[c0];   w1a=ewf[CC+c0];   w2a=ewf[2*CC+c0];   w3a=ewf[3*CC+c0];
    eba=eb16[c0];  bwa=ebnw[c0];     bba=ebnb16[c0];
    w0b=ewf[c0+1]; w1b=ewf[CC+c0+1]; w2b=ewf[2*CC+c0+1]; w3b=ewf[3*CC+c0+1];
    ebb=eb16[c0+1];bwb=ebnw[c0+1];   bbb=ebnb16[c0+1];
  }
  int end = offI[n];
  int start = end - deg_[n];
  int acc0 = 0, acc1 = 0;
  for (int k = start; k < end; ++k){
    int so = srcoff[k];
    int hp = *(const short*)(hq8 + so + c0);
    int h0 = (hp << 24) >> 24;
    int h1 = hp >> 8;
    int e0, e1;
    if (PRE){
      int ep = *(const short*)(eq + ((size_t)k << 7) + c0);
      e0 = (ep << 24) >> 24;
      e1 = ep >> 8;
    } else {
      float4 q = qcsr[k];
      float Sa = q.x*w0a + q.y*w1a + q.z*w2a + q.w*w3a;
      float Sb = q.x*w0b + q.y*w1b + q.z*w2b + q.w*w3b;
      e0 = (int)rq16(rq16(Sa + eba)*bwa + bba);
      e1 = (int)rq16(rq16(Sb + ebb)*bwb + bbb);
    }
    acc0 += min(max(h0 + e0, 0), 127);
    acc1 += min(max(h1 + e1, 0), 127);
  }
  int ua = min(acc0, 127), ub = min(acc1, 127);
  uint bits = (uint)f2bf((float)ua) | ((uint)f2bf((float)ub) << 16);
  *(uint*)(u_bf + (size_t)n*CC + c0) = bits;
}

// ---------------- fused ObjectModel via MFMA bf16 ----------------
// 64-node tile, 4 waves; GEMM1 (K=128 -> H=256) and GEMM2 (K=256 -> C=128)
// exact in bf16/fp32 (integer operands).
__global__ __launch_bounds__(256) void k_om(
    int l, const ushort* __restrict__ u_bf,
    const ushort* __restrict__ W1t, const float* __restrict__ b1q16,
    const float* __restrict__ bnwf, const float* __restrict__ bnb16,
    const ushort* __restrict__ W2t, const float* __restrict__ b2q16,
    const short* __restrict__ h_in, short* __restrict__ h_out,
    signed char* __restrict__ hq8){
  __shared__ ushort uL[64][136];   // pitch 272B: row->+4 banks, 2-way = free
  __shared__ ushort zL[64][264];   // pitch 528B: same
  int t = threadIdx.x;
  int nb = blockIdx.x * 64;
  {  // stage u tile (64x128 bf16)
    int r = t & 63, seg = t >> 6;
    const bf16x8* src = (const bf16x8*)(u_bf + (size_t)(nb + r)*CC + seg*32);
    bf16x8* dst = (bf16x8*)&uL[r][seg*32];
    dst[0] = src[0]; dst[1] = src[1]; dst[2] = src[2]; dst[3] = src[3];
  }
  __syncthreads();
  int lane = t & 63, wv = t >> 6;
  int lr = lane & 15, lk = lane >> 4;
  const f32x4 z4 = {0.f, 0.f, 0.f, 0.f};

  // ---- GEMM1: z1[64 x 256] = u[64 x 128] @ W1 ----
  f32x4 acc[4][4];
  #pragma unroll
  for (int mi=0;mi<4;++mi){
    #pragma unroll
    for (int ci=0;ci<4;++ci) acc[mi][ci] = z4;
  }
  const ushort* W1p = W1t + (size_t)l*HH*CC;
  #pragma unroll
  for (int ks=0; ks<4; ++ks){
    bf16x8 av[4], bv[4];
    #pragma unroll
    for (int mi=0;mi<4;++mi) av[mi] = *(const bf16x8*)&uL[mi*16+lr][ks*32 + lk*8];
    #pragma unroll
    for (int ci=0;ci<4;++ci)
      bv[ci] = *(const bf16x8*)(W1p + (size_t)(wv*64 + ci*16 + lr)*CC + ks*32 + lk*8);
    #pragma unroll
    for (int mi=0;mi<4;++mi){
      #pragma unroll
      for (int ci=0;ci<4;++ci)
        acc[mi][ci] = __builtin_amdgcn_mfma_f32_16x16x32_bf16(av[mi], bv[ci], acc[mi][ci], 0,0,0);
    }
  }
  // epilogue1: requant + BN + ReLU -> zL (bf16)
  #pragma unroll
  for (int ci=0;ci<4;++ci){
    int hcol = wv*64 + ci*16 + lr;
    float b1 = b1q16[l*HH + hcol];
    float bw = bnwf[l*HH + hcol];
    float bb = bnb16[l*HH + hcol];
    #pragma unroll
    for (int mi=0;mi<4;++mi){
      #pragma unroll
      for (int r=0;r<4;++r){
        float v1 = rq16(acc[mi][ci][r] + b1);
        float v2 = fmaxf(rq16(v1*bw + bb), 0.f);
        zL[mi*16 + lk*4 + r][hcol] = f2bf(v2);
      }
    }
  }
  __syncthreads();

  // ---- GEMM2: z2[64 x 128] = z1[64 x 256] @ W2 ----
  f32x4 a2[4][2];
  #pragma unroll
  for (int mi=0;mi<4;++mi){ a2[mi][0] = z4; a2[mi][1] = z4; }
  const ushort* W2p = W2t + (size_t)l*CC*HH;
  #pragma unroll
  for (int ks=0; ks<8; ++ks){
    bf16x8 av[4], bv[2];
    #pragma unroll
    for (int mi=0;mi<4;++mi) av[mi] = *(const bf16x8*)&zL[mi*16+lr][ks*32 + lk*8];
    #pragma unroll
    for (int ci=0;ci<2;++ci)
      bv[ci] = *(const bf16x8*)(W2p + (size_t)(wv*32 + ci*16 + lr)*HH + ks*32 + lk*8);
    #pragma unroll
    for (int mi=0;mi<4;++mi){
      #pragma unroll
      for (int ci=0;ci<2;++ci)
        a2[mi][ci] = __builtin_amdgcn_mfma_f32_16x16x32_bf16(av[mi], bv[ci], a2[mi][ci], 0,0,0);
    }
  }
  // epilogue2: requant + residual; write h16 + clamped int8
  #pragma unroll
  for (int ci=0;ci<2;++ci){
    int ccol = wv*32 + ci*16 + lr;
    float b2 = b2q16[l*CC + ccol];
    #pragma unroll
    for (int mi=0;mi<4;++mi){
      #pragma unroll
      for (int r=0;r<4;++r){
        int node = nb + mi*16 + lk*4 + r;
        float v = rq16(a2[mi][ci][r] + b2);
        int hn = (int)h_in[(size_t)node*CC + ccol] + (int)v;
        h_out[(size_t)node*CC + ccol] = (short)hn;
        hq8[(size_t)node*CC + ccol] = (signed char)min(max(hn, -128), 127);
      }
    }
  }
}

// ---------------- pool + head ----------------
__global__ void k_pool(const short* __restrict__ h, int* __restrict__ pooled){
  int gid = blockIdx.x*256 + threadIdx.x;
  int c = (gid & 63)*2;
  int stride = (gridDim.x*256) >> 6;
  int s0 = 0, s1 = 0;
  for (int n = gid>>6; n < NN; n += stride){
    int v = *(const int*)(h + (size_t)n*CC + c);
    s0 += (int)(short)(v & 0xffff);
    s1 += (v >> 16);
  }
  atomicAdd(&pooled[c], s0);
  atomicAdd(&pooled[c+1], s1);
}

__global__ void k_final(const int* __restrict__ pooled, const float* __restrict__ fcwf,
                        const float* __restrict__ fcb16, float* __restrict__ out){
  __shared__ float red[128];
  int t = threadIdx.x;
  int sc = pooled[t];
  double m = (double)sc / (double)NN;
  float pq = fminf(127.f, fmaxf(-128.f, (float)rint(m)));
  red[t] = pq * fcwf[t];
  __syncthreads();
  for (int o=64;o>0;o>>=1){ if (t<o) red[t] += red[t+o]; __syncthreads(); }
  if (t==0){
    float v = rq16(red[0] + fcb16[0]);
    float o1 = v * 0.0625f;
    float sg = 1.f/(1.f + expf(-o1));
    float oq = fminf(127.f, fmaxf(-128.f, rintf(sg*16.f)));
    out[0] = oq * 0.0625f;
  }
}

extern "C" void kernel_launch(void* const* d_in, const int* in_sizes, int n_in,
                              void* d_out, int out_size, void* d_ws, size_t ws_size,
                              hipStream_t stream){
  (void)in_sizes; (void)n_in; (void)out_size;
  const float* x   = (const float*)d_in[0];
  const float* ea  = (const float*)d_in[1];
  const int*   ei  = (const int*)d_in[2];
  const float* W1  = (const float*)d_in[11];
  const float* W2  = (const float*)d_in[15];

  char* w = (char*)d_ws;
  auto alloc = [&](size_t bytes)->char*{
    char* p = w; w += (bytes + 255) & ~(size_t)255; return p;
  };
  short* h0        = (short*)alloc((size_t)NPAD*CC*2);
  short* h1        = (short*)alloc((size_t)NPAD*CC*2);
  signed char* hq8 = (signed char*)alloc((size_t)NPAD*CC);
  ushort* u_bf     = (ushort*)alloc((size_t)NPAD*CC*2);
  float4* qcsr     = (float4*)alloc((size_t)EE*16);
  int* srcoff      = (int*)alloc((size_t)EE*4);
  int* eidc        = (int*)alloc((size_t)EE*4);
  int* deg         = (int*)alloc(NN*4);
  int* offI        = (int*)alloc(NN*4);
  int* cursor      = (int*)alloc(NN*4);
  int* btot        = (int*)alloc(64*4);
  int* boff        = (int*)alloc(64*4);
  ushort* W1t      = (ushort*)alloc((size_t)LL*CC*HH*2);
  ushort* W2t      = (ushort*)alloc((size_t)LL*CC*HH*2);
  float* nodeWf    = (float*)alloc(3*CC*4);
  float* nb16f     = (float*)alloc(CC*4);
  float* nbnwf     = (float*)alloc(CC*4);
  float* nbnb16f   = (float*)alloc(CC*4);
  float* ewf       = (float*)alloc(4*CC*4);
  float* eb16f     = (float*)alloc(CC*4);
  float* ebnwf     = (float*)alloc(CC*4);
  float* ebnb16f   = (float*)alloc(CC*4);
  float* b1q16f    = (float*)alloc(LL*HH*4);
  float* bnwf      = (float*)alloc(LL*HH*4);
  float* bnb16f    = (float*)alloc(LL*HH*4);
  float* b2q16f    = (float*)alloc(LL*CC*4);
  float* fcwf      = (float*)alloc(CC*4);
  float* fcb16f    = (float*)alloc(256);
  int* pooled      = (int*)alloc(CC*4);
  size_t base_used = (size_t)(w - (char*)d_ws);
  // PRE: materialize edge features int8 in CSR order if workspace allows (+80MB)
  bool PRE = (ws_size >= base_used + (size_t)EE*CC + (16u<<20));
  signed char* eq  = PRE ? (signed char*)alloc((size_t)EE*CC) : nullptr;

  hipMemsetAsync(deg, 0, NN*4, stream);
  hipMemsetAsync(pooled, 0, CC*4, stream);

  k_qbig<<<(LL*CC*HH + 255)/256, 256, 0, stream>>>(W1, W2, W1t, W2t);

  QSArgs qa;
  auto setq = [&](int r, int idx, float* d, int n, float m){
    qa.q[r].s = (const float*)d_in[idx]; qa.q[r].d = d; qa.q[r].n = n; qa.q[r].m = m;
  };
  setq(0, 3,  nodeWf,  3*CC, 1.f);
  setq(1, 4,  nb16f,   CC,   16.f);
  setq(2, 5,  ewf,     4*CC, 1.f);
  setq(3, 6,  eb16f,   CC,   16.f);
  setq(4, 7,  nbnwf,   CC,   1.f);
  setq(5, 8,  nbnb16f, CC,   16.f);
  setq(6, 9,  ebnwf,   CC,   1.f);
  setq(7, 10, ebnb16f, CC,   16.f);
  setq(8, 12, b1q16f,  LL*HH, 16.f);
  setq(9, 13, bnwf,    LL*HH, 1.f);
  setq(10,14, bnb16f,  LL*HH, 16.f);
  setq(11,16, b2q16f,  LL*CC, 16.f);
  setq(12,17, fcwf,    CC,   1.f);
  setq(13,18, fcb16f,  1,    16.f);
  k_qsmall<<<4, 256, 0, stream>>>(qa);

  k_node_enc<<<(NN*CC)/256, 256, 0, stream>>>(x, nodeWf, nb16f, nbnwf, nbnb16f, h0, hq8);
  k_deg<<<(EE+255)/256, 256, 0, stream>>>(ei, deg);
  int nblk = (NN + 1023)/1024;
  k_scanA<<<nblk, 256, 0, stream>>>(deg, offI, btot);
  k_scanB<<<1, 64, 0, stream>>>(btot, boff, nblk);
  k_scanC<<<(NN+255)/256, 256, 0, stream>>>(boff, deg, offI, cursor);
  k_fill<<<(EE+255)/256, 256, 0, stream>>>(ei, cursor, srcoff, eidc);
  k_eperm<<<(EE+255)/256, 256, 0, stream>>>(eidc, ea, qcsr);
  if (PRE)
    k_eenc<<<EE/2, 256, 0, stream>>>(qcsr, ewf, eb16f, ebnwf, ebnb16f, eq);

  for (int l=0;l<LL;++l){
    const short* hi = (l & 1) ? h1 : h0;
    short* ho       = (l & 1) ? h0 : h1;
    if (PRE)
      k_msg<1><<<NN/4, 256, 0, stream>>>(offI, deg, srcoff, qcsr, eq,
                                         ewf, eb16f, ebnwf, ebnb16f, hq8, u_bf);
    else
      k_msg<0><<<NN/4, 256, 0, stream>>>(offI, deg, srcoff, qcsr, eq,
                                         ewf, eb16f, ebnwf, ebnb16f, hq8, u_bf);
    k_om<<<NPAD/64, 256, 0, stream>>>(l, u_bf, W1t, b1q16f, bnwf, bnb16f,
                                      W2t, b2q16f, hi, ho, hq8);
  }
  // after 4 layers the live buffer is h0
  k_pool<<<512, 256, 0, stream>>>(h0, pooled);
  k_final<<<1, 128, 0, stream>>>(pooled, fcwf, fcb16f, (float*)d_out);
}

// Round 3
// 471.915 us; speedup vs baseline: 2.3652x; 1.2902x over previous
//
#include <hip/hip_runtime.h>
#include <stdint.h>

#define NN 50000
#define EE 625000
#define EPAD (EE + 16)   // padding so chunked loads may overrun safely
#define CC 128
#define HH 256
#define LL 4
#define NPAD 50048   // multiple of 64 for k_om tiles

typedef __attribute__((ext_vector_type(8))) short bf16x8;
typedef __attribute__((ext_vector_type(4))) float f32x4;

// Everything lives on the k/16 grid, k in [-128,127]; rintf == round-half-even
// == jnp.round. All sums < 2^24 -> exact fp32 (and exact bf16 MFMA: inputs are
// integers |x|<=128, products <=16129, K-sums <=4.13e6 < 2^24).
__device__ __forceinline__ float qbf(float x){
  return fminf(127.f, fmaxf(-128.f, rintf(x*16.f)));
}
__device__ __forceinline__ float rq16(float t){
  return fminf(127.f, fmaxf(-128.f, rintf(t*0.0625f)));
}
__device__ __forceinline__ ushort f2bf(float v){  // exact for our small ints
  return (ushort)(__float_as_uint(v) >> 16);
}

// ---------------- param quantization ----------------
__global__ void k_qbig(const float* __restrict__ W1, const float* __restrict__ W2,
                       ushort* __restrict__ W1t, ushort* __restrict__ W2t){
  int i = blockIdx.x*256 + threadIdx.x;
  if (i >= LL*CC*HH) return;
  {  // W1 [L][C][H] -> W1t [L][H][C] bf16
    float v = qbf(W1[i]);
    int l = i / (CC*HH); int r = i - l*CC*HH; int c = r / HH; int hh = r - c*HH;
    W1t[((size_t)l*HH + hh)*CC + c] = f2bf(v);
  }
  {  // W2 [L][H][C] -> W2t [L][C][H] bf16
    float v = qbf(W2[i]);
    int l = i / (HH*CC); int r = i - l*HH*CC; int hh = r / CC; int c = r - hh*CC;
    W2t[((size_t)l*CC + c)*HH + hh] = f2bf(v);
  }
}

struct QS { const float* s; float* d; int n; float m; };
struct QSArgs { QS q[14]; };

__global__ void k_qsmall(QSArgs a){
  for (int r=0;r<14;++r){
    QS qs = a.q[r];
    for (int i = blockIdx.x*blockDim.x + threadIdx.x; i < qs.n; i += gridDim.x*blockDim.x)
      qs.d[i] = qs.m * qbf(qs.s[i]);
  }
}

// ---------------- node encoder ----------------
__global__ __launch_bounds__(256) void k_node_enc(
    const float* __restrict__ x, const float* __restrict__ nW,
    const float* __restrict__ nb16, const float* __restrict__ bnw,
    const float* __restrict__ bnb16, short* __restrict__ h0,
    signed char* __restrict__ hq8){
  int idx = blockIdx.x*256 + threadIdx.x;          // grid exact: N*C/256
  int n = idx >> 7, c = idx & 127;
  float x0 = qbf(x[n*3]), x1 = qbf(x[n*3+1]), x2 = qbf(x[n*3+2]);
  float S = x0*nW[c] + x1*nW[CC+c] + x2*nW[2*CC+c];
  float v1 = rq16(S + nb16[c]);
  float v2 = rq16(v1*bnw[c] + bnb16[c]);
  h0[idx] = (short)v2;
  hq8[idx] = (signed char)v2;   // already in [-128,127]
}

// ---------------- CSR build ----------------
__global__ void k_deg(const int* __restrict__ ei, int* __restrict__ deg){
  int e = blockIdx.x*256 + threadIdx.x;
  if (e < EE) atomicAdd(&deg[ei[EE + e]], 1);
}

__global__ __launch_bounds__(256) void k_scanA(const int* __restrict__ deg,
                                               int* __restrict__ offI,
                                               int* __restrict__ btot){
  __shared__ int sh[256];
  int t = threadIdx.x;
  int base = blockIdx.x*1024 + t*4;
  int v[4]; int s = 0;
  #pragma unroll
  for (int i=0;i<4;++i){ v[i] = (base+i < NN) ? deg[base+i] : 0; s += v[i]; }
  sh[t] = s; __syncthreads();
  for (int off=1; off<256; off<<=1){
    int xv = (t>=off) ? sh[t-off] : 0;
    __syncthreads();
    sh[t] += xv;
    __syncthreads();
  }
  int run = (t>0) ? sh[t-1] : 0;
  #pragma unroll
  for (int i=0;i<4;++i){ run += v[i]; if (base+i < NN) offI[base+i] = run; }
  if (t==255) btot[blockIdx.x] = sh[255];
}

__global__ void k_scanB(const int* __restrict__ btot, int* __restrict__ boff, int nblk){
  if (threadIdx.x==0 && blockIdx.x==0){
    int run = 0;
    for (int b=0;b<nblk;++b){ int v = btot[b]; boff[b] = run; run += v; }
  }
}

__global__ void k_scanC(const int* __restrict__ boff, const int* __restrict__ deg,
                        int* __restrict__ offI, int* __restrict__ cursor){
  int i = blockIdx.x*256 + threadIdx.x;
  if (i < NN){
    int v = offI[i] + boff[i>>10];
    offI[i] = v;
    cursor[i] = v - deg[i];
  }
}

// fill CSR: scatter src offset + quantized edge attrs (fuses old k_eperm)
__global__ void k_fill(const int* __restrict__ ei, const float* __restrict__ ea,
                       int* __restrict__ cursor, int* __restrict__ srcoff,
                       float4* __restrict__ qcsr){
  int e = blockIdx.x*256 + threadIdx.x;
  if (e < EE){
    int tgt = ei[EE + e];
    int p = atomicAdd(&cursor[tgt], 1);
    srcoff[p] = ei[e] * CC;
    float4 v = ((const float4*)ea)[e];
    qcsr[p] = make_float4(qbf(v.x), qbf(v.y), qbf(v.z), qbf(v.w));
  }
}

// PRE path: materialize edge feature e (int8) in CSR order, once.
// grid-stride, 4 channels/thread, weights hoisted, char4 packed stores.
__global__ __launch_bounds__(256) void k_eenc(
    const float4* __restrict__ qcsr,
    const float* __restrict__ ewf, const float* __restrict__ eb16,
    const float* __restrict__ ebnw, const float* __restrict__ ebnb16,
    signed char* __restrict__ eq){
  int t = blockIdx.x*256 + threadIdx.x;
  int c0 = (t & 31) * 4;
  float wv0[4], wv1[4], wv2[4], wv3[4], ebv[4], bwv[4], bbv[4];
  #pragma unroll
  for (int j=0;j<4;++j){
    int c = c0 + j;
    wv0[j]=ewf[c]; wv1[j]=ewf[CC+c]; wv2[j]=ewf[2*CC+c]; wv3[j]=ewf[3*CC+c];
    ebv[j]=eb16[c]; bwv[j]=ebnw[c]; bbv[j]=ebnb16[c];
  }
  int stride = (gridDim.x*256) >> 5;
  for (int p = t >> 5; p < EE; p += stride){
    float4 q = qcsr[p];
    uint packed = 0;
    #pragma unroll
    for (int j=0;j<4;++j){
      float S  = q.x*wv0[j] + q.y*wv1[j] + q.z*wv2[j] + q.w*wv3[j];
      float v1 = rq16(S + ebv[j]);
      float ec = rq16(v1*bwv[j] + bbv[j]);
      packed |= ((uint)((int)ec & 0xff)) << (8*j);
    }
    *(uint*)(eq + ((size_t)p << 7) + c0) = packed;
  }
}

// ---------------- per-layer message+aggregate (gather CSR, no atomics) ------
// one wave per node, 2 channels per lane; chunk-16 edge loop:
// one coalesced srcoff load -> readlane SGPR bases -> 32 loads in flight.
template<int PRE>
__global__ __launch_bounds__(256) void k_msg(
    const int* __restrict__ offI, const int* __restrict__ deg_,
    const int* __restrict__ srcoff, const float4* __restrict__ qcsr,
    const signed char* __restrict__ eq,
    const float* __restrict__ ewf, const float* __restrict__ eb16,
    const float* __restrict__ ebnw, const float* __restrict__ ebnb16,
    const signed char* __restrict__ hq8, ushort* __restrict__ u_bf){
  int n = blockIdx.x*4 + (threadIdx.x >> 6);
  int lane = threadIdx.x & 63;
  int c0 = lane*2;
  float w0a,w1a,w2a,w3a,eba,bwa,bba, w0b,w1b,w2b,w3b,ebb,bwb,bbb;
  if (!PRE){
    w0a=ewf[c0];   w1a=ewf[CC+c0];   w2a=ewf[2*CC+c0];   w3a=ewf[3*CC+c0];
    eba=eb16[c0];  bwa=ebnw[c0];     bba=ebnb16[c0];
    w0b=ewf[c0+1]; w1b=ewf[CC+c0+1]; w2b=ewf[2*CC+c0+1]; w3b=ewf[3*CC+c0+1];
    ebb=eb16[c0+1];bwb=ebnw[c0+1];   bbb=ebnb16[c0+1];
  }
  int end = offI[n];
  int start = end - deg_[n];
  int acc0 = 0, acc1 = 0;
  for (int base = start; base < end; base += 16){
    int rem = end - base;
    int so = srcoff[base + min(lane, rem-1)];   // coalesced; dup beyond rem
    ushort hv[16], ev[16];
    #pragma unroll
    for (int j=0;j<16;++j){
      int soj = __builtin_amdgcn_readlane(so, j);
      hv[j] = *(const ushort*)(hq8 + soj + c0);
      if (PRE) ev[j] = *(const ushort*)(eq + (((size_t)(base+j)) << 7) + c0);
    }
    #pragma unroll
    for (int j=0;j<16;++j){
      if (j < rem){
        int h0 = ((int)hv[j] << 24) >> 24;
        int h1 = ((int)(short)hv[j]) >> 8;
        int e0, e1;
        if (PRE){
          e0 = ((int)ev[j] << 24) >> 24;
          e1 = ((int)(short)ev[j]) >> 8;
        } else {
          float4 q = qcsr[base+j];
          float Sa = q.x*w0a + q.y*w1a + q.z*w2a + q.w*w3a;
          float Sb = q.x*w0b + q.y*w1b + q.z*w2b + q.w*w3b;
          e0 = (int)rq16(rq16(Sa + eba)*bwa + bba);
          e1 = (int)rq16(rq16(Sb + ebb)*bwb + bbb);
        }
        acc0 += min(max(h0 + e0, 0), 127);
        acc1 += min(max(h1 + e1, 0), 127);
      }
    }
  }
  int ua = min(acc0, 127), ub = min(acc1, 127);
  uint bits = (uint)f2bf((float)ua) | ((uint)f2bf((float)ub) << 16);
  *(uint*)(u_bf + (size_t)n*CC + c0) = bits;
}

// ---------------- fused ObjectModel via MFMA bf16 ----------------
__global__ __launch_bounds__(256) void k_om(
    int l, const ushort* __restrict__ u_bf,
    const ushort* __restrict__ W1t, const float* __restrict__ b1q16,
    const float* __restrict__ bnwf, const float* __restrict__ bnb16,
    const ushort* __restrict__ W2t, const float* __restrict__ b2q16,
    const short* __restrict__ h_in, short* __restrict__ h_out,
    signed char* __restrict__ hq8){
  __shared__ ushort uL[64][136];   // pitch 272B: row->+4 banks, 2-way = free
  __shared__ ushort zL[64][264];   // pitch 528B: same
  int t = threadIdx.x;
  int nb = blockIdx.x * 64;
  {  // stage u tile (64x128 bf16)
    int r = t & 63, seg = t >> 6;
    const bf16x8* src = (const bf16x8*)(u_bf + (size_t)(nb + r)*CC + seg*32);
    bf16x8* dst = (bf16x8*)&uL[r][seg*32];
    dst[0] = src[0]; dst[1] = src[1]; dst[2] = src[2]; dst[3] = src[3];
  }
  __syncthreads();
  int lane = t & 63, wv = t >> 6;
  int lr = lane & 15, lk = lane >> 4;
  const f32x4 z4 = {0.f, 0.f, 0.f, 0.f};

  // ---- GEMM1: z1[64 x 256] = u[64 x 128] @ W1 ----
  f32x4 acc[4][4];
  #pragma unroll
  for (int mi=0;mi<4;++mi){
    #pragma unroll
    for (int ci=0;ci<4;++ci) acc[mi][ci] = z4;
  }
  const ushort* W1p = W1t + (size_t)l*HH*CC;
  #pragma unroll
  for (int ks=0; ks<4; ++ks){
    bf16x8 av[4], bv[4];
    #pragma unroll
    for (int mi=0;mi<4;++mi) av[mi] = *(const bf16x8*)&uL[mi*16+lr][ks*32 + lk*8];
    #pragma unroll
    for (int ci=0;ci<4;++ci)
      bv[ci] = *(const bf16x8*)(W1p + (size_t)(wv*64 + ci*16 + lr)*CC + ks*32 + lk*8);
    #pragma unroll
    for (int mi=0;mi<4;++mi){
      #pragma unroll
      for (int ci=0;ci<4;++ci)
        acc[mi][ci] = __builtin_amdgcn_mfma_f32_16x16x32_bf16(av[mi], bv[ci], acc[mi][ci], 0,0,0);
    }
  }
  // epilogue1: requant + BN + ReLU -> zL (bf16)
  #pragma unroll
  for (int ci=0;ci<4;++ci){
    int hcol = wv*64 + ci*16 + lr;
    float b1 = b1q16[l*HH + hcol];
    float bw = bnwf[l*HH + hcol];
    float bb = bnb16[l*HH + hcol];
    #pragma unroll
    for (int mi=0;mi<4;++mi){
      #pragma unroll
      for (int r=0;r<4;++r){
        float v1 = rq16(acc[mi][ci][r] + b1);
        float v2 = fmaxf(rq16(v1*bw + bb), 0.f);
        zL[mi*16 + lk*4 + r][hcol] = f2bf(v2);
      }
    }
  }
  __syncthreads();

  // ---- GEMM2: z2[64 x 128] = z1[64 x 256] @ W2 ----
  f32x4 a2[4][2];
  #pragma unroll
  for (int mi=0;mi<4;++mi){ a2[mi][0] = z4; a2[mi][1] = z4; }
  const ushort* W2p = W2t + (size_t)l*CC*HH;
  #pragma unroll
  for (int ks=0; ks<8; ++ks){
    bf16x8 av[4], bv[2];
    #pragma unroll
    for (int mi=0;mi<4;++mi) av[mi] = *(const bf16x8*)&zL[mi*16+lr][ks*32 + lk*8];
    #pragma unroll
    for (int ci=0;ci<2;++ci)
      bv[ci] = *(const bf16x8*)(W2p + (size_t)(wv*32 + ci*16 + lr)*HH + ks*32 + lk*8);
    #pragma unroll
    for (int mi=0;mi<4;++mi){
      #pragma unroll
      for (int ci=0;ci<2;++ci)
        a2[mi][ci] = __builtin_amdgcn_mfma_f32_16x16x32_bf16(av[mi], bv[ci], a2[mi][ci], 0,0,0);
    }
  }
  // epilogue2: requant + residual; write h16 + clamped int8
  #pragma unroll
  for (int ci=0;ci<2;++ci){
    int ccol = wv*32 + ci*16 + lr;
    float b2 = b2q16[l*CC + ccol];
    #pragma unroll
    for (int mi=0;mi<4;++mi){
      #pragma unroll
      for (int r=0;r<4;++r){
        int node = nb + mi*16 + lk*4 + r;
        float v = rq16(a2[mi][ci][r] + b2);
        int hn = (int)h_in[(size_t)node*CC + ccol] + (int)v;
        h_out[(size_t)node*CC + ccol] = (short)hn;
        hq8[(size_t)node*CC + ccol] = (signed char)min(max(hn, -128), 127);
      }
    }
  }
}

// ---------------- pool + head ----------------
__global__ void k_pool(const short* __restrict__ h, int* __restrict__ pooled){
  int gid = blockIdx.x*256 + threadIdx.x;
  int c = (gid & 63)*2;
  int stride = (gridDim.x*256) >> 6;
  int s0 = 0, s1 = 0;
  for (int n = gid>>6; n < NN; n += stride){
    int v = *(const int*)(h + (size_t)n*CC + c);
    s0 += (int)(short)(v & 0xffff);
    s1 += (v >> 16);
  }
  atomicAdd(&pooled[c], s0);
  atomicAdd(&pooled[c+1], s1);
}

__global__ void k_final(const int* __restrict__ pooled, const float* __restrict__ fcwf,
                        const float* __restrict__ fcb16, float* __restrict__ out){
  __shared__ float red[128];
  int t = threadIdx.x;
  int sc = pooled[t];
  double m = (double)sc / (double)NN;
  float pq = fminf(127.f, fmaxf(-128.f, (float)rint(m)));
  red[t] = pq * fcwf[t];
  __syncthreads();
  for (int o=64;o>0;o>>=1){ if (t<o) red[t] += red[t+o]; __syncthreads(); }
  if (t==0){
    float v = rq16(red[0] + fcb16[0]);
    float o1 = v * 0.0625f;
    float sg = 1.f/(1.f + expf(-o1));
    float oq = fminf(127.f, fmaxf(-128.f, rintf(sg*16.f)));
    out[0] = oq * 0.0625f;
  }
}

extern "C" void kernel_launch(void* const* d_in, const int* in_sizes, int n_in,
                              void* d_out, int out_size, void* d_ws, size_t ws_size,
                              hipStream_t stream){
  (void)in_sizes; (void)n_in; (void)out_size;
  const float* x   = (const float*)d_in[0];
  const float* ea  = (const float*)d_in[1];
  const int*   ei  = (const int*)d_in[2];
  const float* W1  = (const float*)d_in[11];
  const float* W2  = (const float*)d_in[15];

  char* w = (char*)d_ws;
  auto alloc = [&](size_t bytes)->char*{
    char* p = w; w += (bytes + 255) & ~(size_t)255; return p;
  };
  short* h0        = (short*)alloc((size_t)NPAD*CC*2);
  short* h1        = (short*)alloc((size_t)NPAD*CC*2);
  signed char* hq8 = (signed char*)alloc((size_t)NPAD*CC);
  ushort* u_bf     = (ushort*)alloc((size_t)NPAD*CC*2);
  float4* qcsr     = (float4*)alloc((size_t)EPAD*16);
  int* srcoff      = (int*)alloc((size_t)EPAD*4);
  int* deg         = (int*)alloc(NN*4);
  int* offI        = (int*)alloc(NN*4);
  int* cursor      = (int*)alloc(NN*4);
  int* btot        = (int*)alloc(64*4);
  int* boff        = (int*)alloc(64*4);
  ushort* W1t      = (ushort*)alloc((size_t)LL*CC*HH*2);
  ushort* W2t      = (ushort*)alloc((size_t)LL*CC*HH*2);
  float* nodeWf    = (float*)alloc(3*CC*4);
  float* nb16f     = (float*)alloc(CC*4);
  float* nbnwf     = (float*)alloc(CC*4);
  float* nbnb16f   = (float*)alloc(CC*4);
  float* ewf       = (float*)alloc(4*CC*4);
  float* eb16f     = (float*)alloc(CC*4);
  float* ebnwf     = (float*)alloc(CC*4);
  float* ebnb16f   = (float*)alloc(CC*4);
  float* b1q16f    = (float*)alloc(LL*HH*4);
  float* bnwf      = (float*)alloc(LL*HH*4);
  float* bnb16f    = (float*)alloc(LL*HH*4);
  float* b2q16f    = (float*)alloc(LL*CC*4);
  float* fcwf      = (float*)alloc(CC*4);
  float* fcb16f    = (float*)alloc(256);
  int* pooled      = (int*)alloc(CC*4);
  size_t base_used = (size_t)(w - (char*)d_ws);
  // PRE: materialize edge features int8 in CSR order if workspace allows (+80MB)
  bool PRE = (ws_size >= base_used + (size_t)EPAD*CC + (16u<<20));
  signed char* eq  = PRE ? (signed char*)alloc((size_t)EPAD*CC) : nullptr;

  hipMemsetAsync(deg, 0, NN*4, stream);
  hipMemsetAsync(pooled, 0, CC*4, stream);

  k_qbig<<<(LL*CC*HH + 255)/256, 256, 0, stream>>>(W1, W2, W1t, W2t);

  QSArgs qa;
  auto setq = [&](int r, int idx, float* d, int n, float m){
    qa.q[r].s = (const float*)d_in[idx]; qa.q[r].d = d; qa.q[r].n = n; qa.q[r].m = m;
  };
  setq(0, 3,  nodeWf,  3*CC, 1.f);
  setq(1, 4,  nb16f,   CC,   16.f);
  setq(2, 5,  ewf,     4*CC, 1.f);
  setq(3, 6,  eb16f,   CC,   16.f);
  setq(4, 7,  nbnwf,   CC,   1.f);
  setq(5, 8,  nbnb16f, CC,   16.f);
  setq(6, 9,  ebnwf,   CC,   1.f);
  setq(7, 10, ebnb16f, CC,   16.f);
  setq(8, 12, b1q16f,  LL*HH, 16.f);
  setq(9, 13, bnwf,    LL*HH, 1.f);
  setq(10,14, bnb16f,  LL*HH, 16.f);
  setq(11,16, b2q16f,  LL*CC, 16.f);
  setq(12,17, fcwf,    CC,   1.f);
  setq(13,18, fcb16f,  1,    16.f);
  k_qsmall<<<4, 256, 0, stream>>>(qa);

  k_node_enc<<<(NN*CC)/256, 256, 0, stream>>>(x, nodeWf, nb16f, nbnwf, nbnb16f, h0, hq8);
  k_deg<<<(EE+255)/256, 256, 0, stream>>>(ei, deg);
  int nblk = (NN + 1023)/1024;
  k_scanA<<<nblk, 256, 0, stream>>>(deg, offI, btot);
  k_scanB<<<1, 64, 0, stream>>>(btot, boff, nblk);
  k_scanC<<<(NN+255)/256, 256, 0, stream>>>(boff, deg, offI, cursor);
  k_fill<<<(EE+255)/256, 256, 0, stream>>>(ei, ea, cursor, srcoff, qcsr);
  if (PRE)
    k_eenc<<<2048, 256, 0, stream>>>(qcsr, ewf, eb16f, ebnwf, ebnb16f, eq);

  for (int l=0;l<LL;++l){
    const short* hi = (l & 1) ? h1 : h0;
    short* ho       = (l & 1) ? h0 : h1;
    if (PRE)
      k_msg<1><<<NN/4, 256, 0, stream>>>(offI, deg, srcoff, qcsr, eq,
                                         ewf, eb16f, ebnwf, ebnb16f, hq8, u_bf);
    else
      k_msg<0><<<NN/4, 256, 0, stream>>>(offI, deg, srcoff, qcsr, eq,
                                         ewf, eb16f, ebnwf, ebnb16f, hq8, u_bf);
    k_om<<<NPAD/64, 256, 0, stream>>>(l, u_bf, W1t, b1q16f, bnwf, bnb16f,
                                      W2t, b2q16f, hi, ho, hq8);
  }
  // after 4 layers the live buffer is h0
  k_pool<<<512, 256, 0, stream>>>(h0, pooled);
  k_final<<<1, 128, 0, stream>>>(pooled, fcwf, fcb16f, (float*)d_out);
}